// Round 14
// baseline (158.781 us; speedup 1.0000x reference)
//
#include <hip/hip_runtime.h>

// Causal MHA forward: B=2 H=16 T=2048 DH=64, fp32 in/out, bf16 MFMA math.
// Round-6 inner loop verbatim (4 waves, 64 q-rows, KBLK=64, dbuf,
// 1 barrier/iter, T14 reg-prefetch, T5 setprio, T13 defer-max).
// NEW: qtiles q>=17 are split into EVEN-k-tile and ODD-k-tile blocks
// (adjacent k => L2 locality preserved); q<=16 run whole. 47 units x 32
// heads = 1504 blocks, max len 17 (vs 32) > 1280 residency slots =>
// backfill + near-flat occupancy. E/O partials (m,l f32; O bf16) merged
// by the round-9-verified merge kernel. Fallback to round-6 if ws small.

constexpr int Bc = 2, Hc = 16, Tc = 2048, Dc = 64;
constexpr float QSCALE = 0.125f * 1.44269504088896340736f; // DH^-0.5 * log2 e

// ws: O-partials bf16 [side][head][p<15][row 64][d 64], then ml f32
// [side][head][p][row][2].  p = q - 17.
constexpr size_t WS_O_BYTES  = 2ull * 32 * 15 * 64 * 64 * 2;  // 15,728,640
constexpr size_t WS_ML_BYTES = 2ull * 32 * 15 * 64 * 2 * 4;   //    983,040
constexpr size_t WS_NEED_BYTES = WS_O_BYTES + WS_ML_BYTES;    // 16,711,680

typedef __attribute__((__ext_vector_type__(8))) __bf16 bf16x8;
typedef __attribute__((__ext_vector_type__(4))) __bf16 bf16x4;
typedef __attribute__((__ext_vector_type__(4))) float f32x4;

template <bool SPLIT>
__device__ __forceinline__ void attn_body(
    const float* __restrict__ Q, const float* __restrict__ K,
    const float* __restrict__ V, float* __restrict__ O,
    __bf16* __restrict__ wsO, float* __restrict__ wsML)
{
  const int tid  = threadIdx.x;
  const int wave = tid >> 6;
  const int lane = tid & 63;
  const int l16  = lane & 15;
  const int g    = lane >> 4;

  const int bid  = blockIdx.x;
  const int head = bid & 31;          // co-resident blocks share head
  const int u    = bid >> 5;          // unit, LPT-ish order
  int q, side; bool whole;
  if (SPLIT) {
    if (u == 0)      { whole = true;  q = 16;               side = 0; }
    else if (u < 31) { whole = false; q = 31 - ((u - 1) >> 1); side = (u - 1) & 1; }
    else             { whole = true;  q = 46 - u;           side = 0; }
  } else {
    whole = true; q = 31 - u; side = 0;
  }
  const int len = whole ? (q + 1) : ((q + 2 - side) >> 1);

  const int b = head >> 4, h = head & 15;
  const int q0 = q * 64 + wave * 16;

  const size_t hoff = (size_t)head * Tc * Dc;
  const float* Qb = Q + hoff;
  const float* Kb = K + hoff;
  const float* Vb = V + hoff;

  // K tile [64 k][64 d] bf16, 128 B rows, byte ^ ((k&7)<<4) swizzle.
  __shared__ __bf16 Kl[2][4096];
  // V^T k-quads: addr(kc,d) = kc*512 + ((d*8) ^ (kc<<3) ^ (((d>>4)&3)<<3))
  // + 2*(k&3). Conflict-free b64 writes and floor reads.
  __shared__ __bf16 Vt[2][4096];

  const int krow = tid >> 2;          // K staging: row; seg = 16-float chunk
  const int seg  = tid & 3;
  const int kswz = (krow & 7) << 4;
  const int vkb  = tid >> 4;          // V staging: k-quad block
  const int vdb  = tid & 15;          // V staging: d-quad
  const int vwx  = (vdb >> 2) << 3;

  // Q as B-operand frag of S^T = K·Q^T: lane l16 = q, regs d = c*32+g*8+j.
  bf16x8 qf[2];
  {
    const float4* qp = (const float4*)(Qb + (size_t)(q0 + l16) * Dc + g * 8);
    #pragma unroll
    for (int c = 0; c < 2; ++c) {
      float4 x0 = qp[c * 8], x1 = qp[c * 8 + 1];
      const float* f0 = (const float*)&x0;
      const float* f1 = (const float*)&x1;
      #pragma unroll
      for (int j = 0; j < 4; ++j) {
        qf[c][j]     = (__bf16)(f0[j] * QSCALE);
        qf[c][4 + j] = (__bf16)(f1[j] * QSCALE);
      }
    }
  }

  f32x4 o_acc[4] = {};
  float m_run = -1e30f, l_run = 0.f;
  float4 kreg[4], vreg[4];

  // ---- Prologue: first tile (t = side for split, 0 for whole) ----
  {
    const int kv0 = (whole ? 0 : side) * 64;
    const float4* kp4 = (const float4*)(Kb + (size_t)(kv0 + krow) * Dc + seg * 16);
    #pragma unroll
    for (int c = 0; c < 4; ++c) kreg[c] = kp4[c];
    const float* vb0 = Vb + (size_t)(kv0 + vkb * 4) * Dc + vdb * 4;
    #pragma unroll
    for (int r = 0; r < 4; ++r) vreg[r] = *(const float4*)(vb0 + r * Dc);

    #pragma unroll
    for (int hh = 0; hh < 2; ++hh) {
      const float* x0 = (const float*)&kreg[2 * hh];
      const float* x1 = (const float*)&kreg[2 * hh + 1];
      bf16x8 t;
      #pragma unroll
      for (int j = 0; j < 4; ++j) { t[j] = (__bf16)x0[j]; t[4 + j] = (__bf16)x1[j]; }
      *(bf16x8*)((char*)Kl[0] + krow * 128 + ((seg * 32 + hh * 16) ^ kswz)) = t;
    }
    #pragma unroll
    for (int i = 0; i < 4; ++i) {
      bf16x4 t;
      #pragma unroll
      for (int r = 0; r < 4; ++r) t[r] = (__bf16)((const float*)&vreg[r])[i];
      const int d = vdb * 4 + i;
      *(bf16x4*)((char*)Vt[0] + vkb * 512 + ((d * 8) ^ (vkb << 3) ^ vwx)) = t;
    }
  }

  for (int j = 0; j < len; ++j) {
    const int t = whole ? j : (2 * j + side);   // absolute k-tile
    __syncthreads();   // buf[cur] staged; other buffer free
    const int cur = j & 1;

    // ---- T14: next tile's global loads land during compute ----
    const bool more = (j + 1 < len);
    if (more) {
      const int kv1 = (whole ? (t + 1) : (t + 2)) * 64;
      const float4* kp4 = (const float4*)(Kb + (size_t)(kv1 + krow) * Dc + seg * 16);
      #pragma unroll
      for (int c = 0; c < 4; ++c) kreg[c] = kp4[c];
      const float* vb0 = Vb + (size_t)(kv1 + vkb * 4) * Dc + vdb * 4;
      #pragma unroll
      for (int r = 0; r < 4; ++r) vreg[r] = *(const float4*)(vb0 + r * Dc);
    }

    const bool partial = (t == q);              // diagonal k-tile
    const int  ns = partial ? (wave + 1) : 4;

    // ---- S^T = K·Q^T: sacc[s] k = t*64+s*16+g*4+r, q = q0+l16 ----
    f32x4 sacc[4];
    __builtin_amdgcn_s_setprio(1);
    #pragma unroll
    for (int s = 0; s < 4; ++s) {
      if (s < ns) {  // wave-uniform
        f32x4 z = {0.f, 0.f, 0.f, 0.f};
        const int row = s * 16 + l16;
        const char* kb = (const char*)Kl[cur] + row * 128;
        const int swz = (row & 7) << 4;
        bf16x8 k0 = *(const bf16x8*)(kb + ((g * 16) ^ swz));
        bf16x8 k1 = *(const bf16x8*)(kb + ((64 + g * 16) ^ swz));
        z = __builtin_amdgcn_mfma_f32_16x16x32_bf16(k0, qf[0], z, 0, 0, 0);
        z = __builtin_amdgcn_mfma_f32_16x16x32_bf16(k1, qf[1], z, 0, 0, 0);
        sacc[s] = z;
      } else {
        sacc[s] = f32x4{-INFINITY, -INFINITY, -INFINITY, -INFINITY};
      }
    }
    __builtin_amdgcn_s_setprio(0);
    if (partial) {  // diagonal mask (absolute indices collapse to this)
      #pragma unroll
      for (int s = 0; s < 4; ++s)
        #pragma unroll
        for (int r = 0; r < 4; ++r)
          if (s * 16 + g * 4 + r > wave * 16 + l16) sacc[s][r] = -INFINITY;
    }

    // ---- Online softmax for q-row l16 (4 g-replicas), tree reduce ----
    float v16[16];
    #pragma unroll
    for (int s = 0; s < 4; ++s)
      #pragma unroll
      for (int r = 0; r < 4; ++r) v16[s * 4 + r] = sacc[s][r];
    #pragma unroll
    for (int w = 8; w >= 1; w >>= 1)
      #pragma unroll
      for (int i = 0; i < 8; ++i)
        if (i < w) v16[i] = fmaxf(v16[i], v16[i + w]);
    float mx = v16[0];
    mx = fmaxf(mx, __shfl_xor(mx, 16, 64));
    mx = fmaxf(mx, __shfl_xor(mx, 32, 64));

    // T13 defer-max: skip rescale while max growth < 8.
    if (!__all(mx <= m_run + 8.0f)) {
      const float mn = fmaxf(m_run, mx);
      const float f  = __builtin_amdgcn_exp2f(m_run - mn);
      m_run = mn;
      l_run *= f;
      #pragma unroll
      for (int r = 0; r < 4; ++r) {
        const float fo = __shfl(f, g * 4 + r, 64);
        #pragma unroll
        for (int dt = 0; dt < 4; ++dt) o_acc[dt][r] *= fo;
      }
    }

    float pv16[16];
    bf16x8 pa[2];
    #pragma unroll
    for (int c = 0; c < 2; ++c)
      #pragma unroll
      for (int j2 = 0; j2 < 8; ++j2) {
        const float pv = __builtin_amdgcn_exp2f(sacc[2 * c + (j2 >> 2)][j2 & 3] - m_run);
        pv16[c * 8 + j2] = pv;
        pa[c][j2] = (__bf16)pv;
      }
    #pragma unroll
    for (int w = 8; w >= 1; w >>= 1)
      #pragma unroll
      for (int i = 0; i < 8; ++i)
        if (i < w) pv16[i] += pv16[i + w];
    float sum = pv16[0];
    sum += __shfl_xor(sum, 16, 64);
    sum += __shfl_xor(sum, 32, 64);
    l_run += sum;

    // ---- PV: O += P(16x64)·V(64x64), both operands in pi k-order ----
    __builtin_amdgcn_s_setprio(1);
    #pragma unroll
    for (int dt = 0; dt < 4; ++dt) {
      const int d = dt * 16 + l16;
      const int dx = (dt & 3) << 3;
      #pragma unroll
      for (int c = 0; c < 2; ++c) {
        const int kc0 = 8 * c + g;
        const int kc1 = 8 * c + 4 + g;
        union { bf16x8 v8; bf16x4 v4[2]; } uu;
        uu.v4[0] = *(const bf16x4*)((char*)Vt[cur] + kc0 * 512 + ((d * 8) ^ (kc0 << 3) ^ dx));
        uu.v4[1] = *(const bf16x4*)((char*)Vt[cur] + kc1 * 512 + ((d * 8) ^ (kc1 << 3) ^ dx));
        o_acc[dt] = __builtin_amdgcn_mfma_f32_16x16x32_bf16(pa[c], uu.v8, o_acc[dt], 0, 0, 0);
      }
    }
    __builtin_amdgcn_s_setprio(0);

    // ---- Write prefetched tile into the other buffer ----
    if (more) {
      const int nxt = cur ^ 1;
      #pragma unroll
      for (int hh = 0; hh < 2; ++hh) {
        const float* x0 = (const float*)&kreg[2 * hh];
        const float* x1 = (const float*)&kreg[2 * hh + 1];
        bf16x8 tt;
        #pragma unroll
        for (int j2 = 0; j2 < 4; ++j2) { tt[j2] = (__bf16)x0[j2]; tt[4 + j2] = (__bf16)x1[j2]; }
        *(bf16x8*)((char*)Kl[nxt] + krow * 128 + ((seg * 32 + hh * 16) ^ kswz)) = tt;
      }
      #pragma unroll
      for (int i = 0; i < 4; ++i) {
        bf16x4 tt;
        #pragma unroll
        for (int r = 0; r < 4; ++r) tt[r] = (__bf16)((const float*)&vreg[r])[i];
        const int d = vdb * 4 + i;
        *(bf16x4*)((char*)Vt[nxt] + vkb * 512 + ((d * 8) ^ (vkb << 3) ^ vwx)) = tt;
      }
    }
  }

  if (whole) {
    // ---- FINAL: out[b][q][h*64+d] = o / l ----
    #pragma unroll
    for (int r = 0; r < 4; ++r) {
      const float il = __shfl(l_run, g * 4 + r, 64);
      const float inv = 1.f / il;
      float* orow = O + ((size_t)b * Tc + (q0 + g * 4 + r)) * (Hc * Dc) + h * Dc;
      #pragma unroll
      for (int dt = 0; dt < 4; ++dt)
        orow[dt * 16 + l16] = o_acc[dt][r] * inv;
    }
  } else {
    // ---- PARTIAL: unnormalized O (bf16) + (m,l f32) to ws ----
    const size_t base = (((size_t)side * 32 + head) * 15 + (q - 17)) * 64;
    #pragma unroll
    for (int r = 0; r < 4; ++r) {
      const int row = wave * 16 + g * 4 + r;
      #pragma unroll
      for (int dt = 0; dt < 4; ++dt)
        wsO[(base + row) * 64 + dt * 16 + l16] = (__bf16)o_acc[dt][r];
    }
    if (g == 0) {
      const size_t mlb = (base + wave * 16 + l16) * 2;
      wsML[mlb]     = m_run;
      wsML[mlb + 1] = l_run;
    }
  }
}

__global__ __launch_bounds__(256, 5) void attn_fwd_split(
    const float* __restrict__ Q, const float* __restrict__ K,
    const float* __restrict__ V, float* __restrict__ O,
    __bf16* __restrict__ wsO, float* __restrict__ wsML)
{
  attn_body<true>(Q, K, V, O, wsO, wsML);
}

// Fallback: round-6 schedule, single kernel, no ws.
__global__ __launch_bounds__(256, 4) void attn_fwd_whole(
    const float* __restrict__ Q, const float* __restrict__ K,
    const float* __restrict__ V, float* __restrict__ O)
{
  attn_body<false>(Q, K, V, O, nullptr, nullptr);
}

// Merge q>=17 rows: 32 heads x 15 p x 64 rows = 30720; 4 rows/block.
__global__ __launch_bounds__(256) void attn_merge(
    const __bf16* __restrict__ wsO, const float* __restrict__ wsML,
    float* __restrict__ O)
{
  const int gr = blockIdx.x * 4 + (threadIdx.x >> 6); // 0..30719
  const int d  = threadIdx.x & 63;
  const int head = gr / 960;                 // 15 p x 64 rows per head
  const int rem  = gr - head * 960;
  const int p    = rem >> 6;                 // 0..14  (q = 17 + p)
  const int row  = rem & 63;
  const int qrow = (17 + p) * 64 + row;
  const int b = head >> 4, h = head & 15;

  const size_t bA = (((size_t)0 * 32 + head) * 15 + p) * 64 + row;
  const size_t bB = (((size_t)1 * 32 + head) * 15 + p) * 64 + row;

  const float mA = wsML[bA * 2], lA = wsML[bA * 2 + 1];
  const float mB = wsML[bB * 2], lB = wsML[bB * 2 + 1];
  const float m  = fmaxf(mA, mB);
  const float wA = __builtin_amdgcn_exp2f(mA - m);
  const float wB = __builtin_amdgcn_exp2f(mB - m);
  const float inv = 1.f / (wA * lA + wB * lB);

  const float o = (wA * (float)wsO[bA * 64 + d] + wB * (float)wsO[bB * 64 + d]) * inv;
  O[((size_t)b * Tc + qrow) * (Hc * Dc) + h * 64 + d] = o;
}

extern "C" void kernel_launch(void* const* d_in, const int* in_sizes, int n_in,
                              void* d_out, int out_size, void* d_ws, size_t ws_size,
                              hipStream_t stream) {
  const float* q = (const float*)d_in[0];
  const float* k = (const float*)d_in[1];
  const float* v = (const float*)d_in[2];
  float* out = (float*)d_out;

  if (ws_size >= WS_NEED_BYTES) {
    __bf16* wsO  = (__bf16*)d_ws;
    float*  wsML = (float*)((char*)d_ws + WS_O_BYTES);
    hipLaunchKernelGGL(attn_fwd_split, dim3(1504), dim3(256), 0, stream,
                       q, k, v, out, wsO, wsML);
    hipLaunchKernelGGL(attn_merge, dim3(7680), dim3(256), 0, stream,
                       wsO, wsML, out);
  } else {
    hipLaunchKernelGGL(attn_fwd_whole, dim3(1024), dim3(256), 0, stream,
                       q, k, v, out);
  }
}